// Round 7
// baseline (172.324 us; speedup 1.0000x reference)
//
#include <hip/hip_runtime.h>
#include <hip/hip_bf16.h>
#include <cstdint>
#include <cstddef>

// Problem constants (DialogueRNNCell: B=4096, T=128, P=2, all feature dims 256)
#define B_N   4096
#define T_N   128
#define P_N   2
#define D     256
#define NG    768                  // 3*D gate width
#define BD    (B_N * D)            // elements per g_hist time slice

typedef __attribute__((ext_vector_type(4))) float f32x4;
typedef __attribute__((ext_vector_type(8))) short bf16x8;
typedef __attribute__((ext_vector_type(8))) unsigned short ushort8;

__device__ __forceinline__ unsigned short f2bf(float f) {
    __hip_bfloat16 h = __float2bfloat16(f);
    return *reinterpret_cast<unsigned short*>(&h);
}

// ---------------------------------------------------------------------------
// Batched f32 -> bf16 conversion (weights + U + e0 + g_last), 8 elems/thread
// ---------------------------------------------------------------------------
struct CvtJobs {
    const float*     src[9];
    unsigned short*  dst[9];
    int              n[9];
};

__global__ __launch_bounds__(256) void cvt_batch(CvtJobs jobs)
{
    const int j = blockIdx.y;
    const int i = (blockIdx.x * 256 + threadIdx.x) * 8;
    if (i >= jobs.n[j]) return;
    const float4* s = reinterpret_cast<const float4*>(jobs.src[j] + i);
    const float4 v0 = s[0], v1 = s[1];
    ushort8 o = { f2bf(v0.x), f2bf(v0.y), f2bf(v0.z), f2bf(v0.w),
                  f2bf(v1.x), f2bf(v1.y), f2bf(v1.z), f2bf(v1.w) };
    *reinterpret_cast<ushort8*>(jobs.dst[j] + i) = o;
}

// ---------------------------------------------------------------------------
// Fused attention over history: one pass, online softmax. One wave per b.
// c_ emitted in bf16 (only consumed as a GEMM operand).
// ---------------------------------------------------------------------------
__global__ __launch_bounds__(256) void attn_kernel(
    const float* __restrict__ g_hist, const float* __restrict__ attn_w,
    unsigned short* __restrict__ c_bf, float* __restrict__ alpha_out)
{
    const int lane = threadIdx.x & 63;
    const int wid  = threadIdx.x >> 6;
    const int b    = blockIdx.x * 4 + wid;

    const float4 w4 = *reinterpret_cast<const float4*>(attn_w + lane * 4);
    const float* gbase = g_hist + (size_t)b * D + lane * 4;

    float  m = -INFINITY, l = 0.f;
    float4 acc = {0.f, 0.f, 0.f, 0.f};
    float  s0 = 0.f, s1 = 0.f;   // per-lane stash of raw scores (t&63==lane)

    auto step = [&](int t, const float4& g) {
        float dot = g.x * w4.x + g.y * w4.y + g.z * w4.z + g.w * w4.w;
        #pragma unroll
        for (int off = 32; off >= 1; off >>= 1)
            dot += __shfl_xor(dot, off, 64);
        const float mn   = fmaxf(m, dot);
        const float corr = __expf(m - mn);     // t==0: exp(-inf)=0, zeroes stale state
        const float p    = __expf(dot - mn);
        l = l * corr + p;
        acc.x = fmaf(p, g.x, acc.x * corr);
        acc.y = fmaf(p, g.y, acc.y * corr);
        acc.z = fmaf(p, g.z, acc.z * corr);
        acc.w = fmaf(p, g.w, acc.w * corr);
        m = mn;
        if ((t & 63) == lane) { if (t & 64) s1 = dot; else s0 = dot; }
    };

    for (int t = 0; t < T_N; t += 2) {
        const float4 g0 = *reinterpret_cast<const float4*>(gbase + (size_t)t * BD);
        const float4 g1 = *reinterpret_cast<const float4*>(gbase + (size_t)(t + 1) * BD);
        step(t, g0);
        step(t + 1, g1);
    }

    const float rl = 1.f / l;
    ushort4 cv = { f2bf(acc.x * rl), f2bf(acc.y * rl),
                   f2bf(acc.z * rl), f2bf(acc.w * rl) };
    *reinterpret_cast<ushort4*>(c_bf + (size_t)b * D + lane * 4) = cv;
    alpha_out[(size_t)b * T_N + lane]      = __expf(s0 - m) * rl;
    alpha_out[(size_t)b * T_N + 64 + lane] = __expf(s1 - m) * rl;
}

// ---------------------------------------------------------------------------
// Fully fused GRU with 3-deep pipelined staging, 64-row tiles (2 blocks/CU).
// GEMM (gi = [A0|A1]@Wi^T, gh = Ah@Wh^T) + gate epilogue in one kernel.
// Block = 64 A-rows x 32 gate-cols; W-tile = rows {c0,c0+256,c0+512}+32
// (96 rows padded to 128 by duplication). BK=32, 16x16x32 MFMA, 4 waves;
// each wave owns 16 rows x 96 gate-cols (acc[6]).
// global_load_lds w=16; 16B-slot XOR swizzle phys = s ^ ((row>>1)&3) applied
// on the global SOURCE (linear LDS dest) and on the ds_read side.
// Pipeline: 3 LDS buffers (12 KB each); stage(s+2) issued each iter; counted
// s_waitcnt vmcnt(6) (2 stages x 3 loads/wave in flight) — never drain
// vmcnt(0) mid-loop.  kcolA and kcolW SEPARATE (round-3 lesson).
//   MODE 0: out_f32[row*256+col] = val   (h = hsrc[row*256+col])
//   MODE 1: party — h = q0[row,qm,col]; writes q_out both slots + qs bf16
// ---------------------------------------------------------------------------
template<int MODE, int NI, int LDWI>
__global__ __launch_bounds__(256) void fused_gru(
    const unsigned short* __restrict__ A0,
    const unsigned short* __restrict__ A1,   // second K half (NI==16) or unused
    const unsigned short* __restrict__ Wi,
    const float* __restrict__ bi,
    const unsigned short* __restrict__ Ah,
    const unsigned short* __restrict__ Wh,
    const float* __restrict__ bh,
    const float* __restrict__ hsrc,          // MODE0: [M,256]; MODE1: q0 [M,2,256]
    const int*  __restrict__ qm,             // MODE1 only
    float* __restrict__ out_f32,             // MODE0: [M,256]; MODE1: q_out [M,2,256]
    unsigned short* __restrict__ out_bf)     // MODE1: qs_sel bf16
{
    constexpr int NT = NI + 8;               // total K-steps (input + hidden)

    const int r0 = blockIdx.x * 64;
    const int c0 = blockIdx.y * 32;

    // per buffer: A 64x32 (2048 ush) | W 128x32 (4096 ush) = 6144 ush = 12 KB
    __shared__ unsigned short smem[3 * 6144];

    const int tid  = threadIdx.x;
    const int lane = tid & 63;
    const int wid  = tid >> 6;

    const int st_row = lane >> 2;       // 0..15
    const int st_p   = lane & 3;        // physical 16B slot

    f32x4 accI[6] = {};
    f32x4 accH[6] = {};

    // issue the 3 global_load_lds (1 A + 2 W) for step `step` into buffer `buf`
    auto stage = [&](int step, int buf) {
        const unsigned short* Apart;
        const unsigned short* W;
        int kcolA, kcolW, ldw;
        if (step < NI) {
            const int kt = step * 32;
            Apart = (kt < D) ? A0 : A1;
            kcolA = kt & (D - 1);
            kcolW = kt;
            W     = Wi;
            ldw   = LDWI;
        } else {
            const int kt = (step - NI) * 32;
            Apart = Ah;
            kcolA = kt;
            kcolW = kt;
            W     = Wh;
            ldw   = D;
        }
        unsigned short* As = smem + buf * 6144;
        unsigned short* Ws = As + 2048;
        // A: one call per wave, rows wid*16 + st_row (0..63)
        {
            const int row  = wid * 16 + st_row;
            const int scol = (st_p ^ ((row >> 1) & 3)) * 8;
            __builtin_amdgcn_global_load_lds(
                (const __attribute__((address_space(1))) void*)
                    (Apart + (size_t)(r0 + row) * D + kcolA + scol),
                (__attribute__((address_space(3))) void*)
                    (As + wid * 512), 16, 0, 0);
        }
        // W: two calls per wave, rows wid*32 + c*16 + st_row (0..127)
        #pragma unroll
        for (int c = 0; c < 2; ++c) {
            const int row  = wid * 32 + c * 16 + st_row;
            const int scol = (st_p ^ ((row >> 1) & 3)) * 8;
            int grp = row >> 5; if (grp == 3) grp = 2;            // pad rows dup
            const int wrow = grp * 256 + c0 + (row & 31);
            __builtin_amdgcn_global_load_lds(
                (const __attribute__((address_space(1))) void*)
                    (W + (size_t)wrow * ldw + kcolW + scol),
                (__attribute__((address_space(3))) void*)
                    (Ws + wid * 1024 + c * 512), 16, 0, 0);
        }
    };

    // ds_read fragments from buffer `buf` and accumulate 6 MFMAs
    auto compute = [&](int buf, f32x4 (&acc)[6]) {
        const unsigned short* As = smem + buf * 6144;
        const unsigned short* Ws = As + 2048;
        const int s  = lane >> 4;        // logical k-slot 0..3
        const int fr = lane & 15;
        bf16x8 a, b[6];
        {
            const int row = wid * 16 + fr;
            const int ph  = s ^ ((row >> 1) & 3);
            a = *reinterpret_cast<const bf16x8*>(&As[row * 32 + ph * 8]);
        }
        #pragma unroll
        for (int j = 0; j < 6; ++j) {
            const int row = j * 16 + fr;
            const int ph  = s ^ ((row >> 1) & 3);
            b[j] = *reinterpret_cast<const bf16x8*>(&Ws[row * 32 + ph * 8]);
        }
        #pragma unroll
        for (int j = 0; j < 6; ++j)
            acc[j] = __builtin_amdgcn_mfma_f32_16x16x32_bf16(
                a, b[j], acc[j], 0, 0, 0);
    };

    // prologue: 2 stages in flight
    stage(0, 0);
    stage(1, 1);

    int cb = 0, ib = 2;
    for (int s = 0; s < NT; ++s) {
        if (s + 2 < NT) stage(s + 2, ib);
        const int rem = NT - 1 - s;
        if (rem >= 2)      asm volatile("s_waitcnt vmcnt(6)" ::: "memory");
        else if (rem == 1) asm volatile("s_waitcnt vmcnt(3)" ::: "memory");
        else               asm volatile("s_waitcnt vmcnt(0)" ::: "memory");
        __builtin_amdgcn_sched_barrier(0);
        __builtin_amdgcn_s_barrier();        // all waves' step-s writes visible
        if (s < NI) compute(cb, accI);
        else        compute(cb, accH);
        __builtin_amdgcn_s_barrier();        // reads done before buf rewrite
        cb = (cb == 2) ? 0 : cb + 1;
        ib = (ib == 2) ? 0 : ib + 1;
    }

    // ---- gate epilogue (thread-local: r/z/n fragments share (row,col)) ----
    const int cr = (lane >> 4) * 4;
    const int cc = lane & 15;
    #pragma unroll
    for (int jj = 0; jj < 2; ++jj) {
        const int col = c0 + jj * 16 + cc;
        const float bir = bi[col],       bhr = bh[col];
        const float biz = bi[col + 256], bhz = bh[col + 256];
        const float bin = bi[col + 512], bhn = bh[col + 512];
        #pragma unroll
        for (int q = 0; q < 4; ++q) {
            const int row = r0 + wid * 16 + cr + q;
            const float ir  = accI[jj][q]     + bir;
            const float hr  = accH[jj][q]     + bhr;
            const float iz  = accI[jj + 2][q] + biz;
            const float hz  = accH[jj + 2][q] + bhz;
            const float in_ = accI[jj + 4][q] + bin;
            const float hn  = accH[jj + 4][q] + bhn;
            const float rg = 1.f / (1.f + __expf(-(ir + hr)));
            const float zg = 1.f / (1.f + __expf(-(iz + hz)));
            const float ng = tanhf(in_ + rg * hn);
            if (MODE == 1) {
                const int p = qm[row];
                const float hv  = hsrc[(size_t)row * 512 + (size_t)p * 256 + col];
                const float ov  = hsrc[(size_t)row * 512 + (size_t)(1 - p) * 256 + col];
                const float val = (1.f - zg) * ng + zg * hv;
                out_f32[(size_t)row * 512 + (size_t)p * 256 + col]       = val;
                out_f32[(size_t)row * 512 + (size_t)(1 - p) * 256 + col] = ov;
                out_bf[(size_t)row * 256 + col] = f2bf(val);
            } else {
                const float hv  = hsrc[(size_t)row * 256 + col];
                const float val = (1.f - zg) * ng + zg * hv;
                out_f32[(size_t)row * 256 + col] = val;
            }
        }
    }
}

// gather the speaking party's q0 row -> bf16 (GEMM operand only)
__global__ __launch_bounds__(256) void gather_q0(
    const float* __restrict__ q0, const int* __restrict__ qm,
    unsigned short* __restrict__ q0_sel_bf)
{
    const int i   = blockIdx.x * 256 + threadIdx.x;   // over B*D/4
    const int row = i >> 6;
    const int j   = (i & 63) * 4;
    const float4 v = *reinterpret_cast<const float4*>(
        q0 + ((size_t)row * P_N + qm[row]) * D + j);
    ushort4 bv = { f2bf(v.x), f2bf(v.y), f2bf(v.z), f2bf(v.w) };
    *reinterpret_cast<ushort4*>(q0_sel_bf + (size_t)row * D + j) = bv;
}

// ---------------------------------------------------------------------------
extern "C" void kernel_launch(void* const* d_in, const int* in_sizes, int n_in,
                              void* d_out, int out_size, void* d_ws, size_t ws_size,
                              hipStream_t stream)
{
    const float* U      = (const float*)d_in[0];
    const int*   qm     = (const int*)  d_in[1];
    const float* g_hist = (const float*)d_in[2];
    const float* q0     = (const float*)d_in[3];
    const float* e0     = (const float*)d_in[4];
    const float* wg_ih  = (const float*)d_in[5];
    const float* wg_hh  = (const float*)d_in[6];
    const float* bg_ih  = (const float*)d_in[7];
    const float* bg_hh  = (const float*)d_in[8];
    const float* wp_ih  = (const float*)d_in[9];
    const float* wp_hh  = (const float*)d_in[10];
    const float* bp_ih  = (const float*)d_in[11];
    const float* bp_hh  = (const float*)d_in[12];
    const float* we_ih  = (const float*)d_in[13];
    const float* we_hh  = (const float*)d_in[14];
    const float* be_ih  = (const float*)d_in[15];
    const float* be_hh  = (const float*)d_in[16];
    const float* attn_w = (const float*)d_in[17];

    float* out   = (float*)d_out;
    float* g_out = out;                       // [B, 256]
    float* q_out = out + 1048576;             // [B, 2, 256]
    float* e_out = out + 3145728;             // [B, 256]
    float* a_out = out + 4194304;             // [B, 1, 128]

    // workspace: all bf16 staging buffers
    unsigned short* bf = (unsigned short*)d_ws;
    unsigned short* U_bf     = bf;                 // 1048576
    unsigned short* e0_bf    = bf + 1048576;
    unsigned short* glast_bf = bf + 2097152;
    unsigned short* q0sel_bf = bf + 3145728;
    unsigned short* c_bf     = bf + 4194304;
    unsigned short* qssel_bf = bf + 5242880;
    unsigned short* wgih_bf  = bf + 6291456;       // 393216
    unsigned short* wpih_bf  = bf + 6684672;       // 393216
    unsigned short* wghh_bf  = bf + 7077888;       // 196608
    unsigned short* wphh_bf  = bf + 7274496;
    unsigned short* weih_bf  = bf + 7471104;
    unsigned short* wehh_bf  = bf + 7667712;       // end 7864320 elems (15.7 MB)

    const float* g_last = g_hist + (size_t)(T_N - 1) * BD;

    const dim3 blk(256);
    const dim3 gridGru(B_N / 64, D / 32);          // 512 blocks, 2/CU

    CvtJobs jobs;
    jobs.src[0] = wg_ih;  jobs.dst[0] = wgih_bf;  jobs.n[0] = NG * 512;
    jobs.src[1] = wg_hh;  jobs.dst[1] = wghh_bf;  jobs.n[1] = NG * 256;
    jobs.src[2] = wp_ih;  jobs.dst[2] = wpih_bf;  jobs.n[2] = NG * 512;
    jobs.src[3] = wp_hh;  jobs.dst[3] = wphh_bf;  jobs.n[3] = NG * 256;
    jobs.src[4] = we_ih;  jobs.dst[4] = weih_bf;  jobs.n[4] = NG * 256;
    jobs.src[5] = we_hh;  jobs.dst[5] = wehh_bf;  jobs.n[5] = NG * 256;
    jobs.src[6] = U;      jobs.dst[6] = U_bf;     jobs.n[6] = B_N * D;
    jobs.src[7] = e0;     jobs.dst[7] = e0_bf;    jobs.n[7] = B_N * D;
    jobs.src[8] = g_last; jobs.dst[8] = glast_bf; jobs.n[8] = B_N * D;
    cvt_batch<<<dim3(B_N * D / 8 / 256, 9), blk, 0, stream>>>(jobs);

    gather_q0<<<B_N * D / 4 / 256, blk, 0, stream>>>(q0, qm, q0sel_bf);
    attn_kernel<<<B_N / 4, blk, 0, stream>>>(g_hist, attn_w, c_bf, a_out);

    // global GRU: x = [U | q0_sel], h = g_hist[-1] -> g_out
    fused_gru<0, 16, 512><<<gridGru, blk, 0, stream>>>(
        U_bf, q0sel_bf, wgih_bf, bg_ih,
        glast_bf, wghh_bf, bg_hh,
        g_last, nullptr, g_out, nullptr);

    // party GRU (speaker slot): x = [U | c_], h = q0[b,qm]; writes q_out + qs bf16
    fused_gru<1, 16, 512><<<gridGru, blk, 0, stream>>>(
        U_bf, c_bf, wpih_bf, bp_ih,
        q0sel_bf, wphh_bf, bp_hh,
        q0, qm, q_out, qssel_bf);

    // emotion GRU: x = qs_sel, h = e0 -> e_out
    fused_gru<0, 8, 256><<<gridGru, blk, 0, stream>>>(
        qssel_bf, nullptr, weih_bf, be_ih,
        e0_bf, wehh_bf, be_hh,
        e0, nullptr, e_out, nullptr);
}

// Round 9
// 162.049 us; speedup vs baseline: 1.0634x; 1.0634x over previous
//
#include <hip/hip_runtime.h>
#include <hip/hip_bf16.h>
#include <cstdint>
#include <cstddef>

// Problem constants (DialogueRNNCell: B=4096, T=128, P=2, all feature dims 256)
#define B_N   4096
#define T_N   128
#define P_N   2
#define D     256
#define NG    768                  // 3*D gate width
#define BD    (B_N * D)            // elements per g_hist time slice
#define AGRID 1024                 // attn_fused grid
#define AGSIZE (AGRID * 256)

typedef __attribute__((ext_vector_type(4))) float f32x4;
typedef __attribute__((ext_vector_type(8))) short bf16x8;
typedef __attribute__((ext_vector_type(8))) unsigned short ushort8;

__device__ __forceinline__ unsigned short f2bf(float f) {
    __hip_bfloat16 h = __float2bfloat16(f);
    return *reinterpret_cast<unsigned short*>(&h);
}

// ---------------------------------------------------------------------------
// Params structs
// ---------------------------------------------------------------------------
struct AttnParams {
    const float *U, *g_hist, *q0, *e0;
    const int   *qm;
    const float *wg_ih, *wg_hh, *wp_ih, *wp_hh, *we_ih, *we_hh;
    const float *attn_w;
    float *a_out;
    unsigned short *U_bf, *e0_bf, *glast_bf, *q0sel_bf, *c_bf;
    unsigned short *wgih_bf, *wpih_bf, *wghh_bf, *wphh_bf, *weih_bf, *wehh_bf;
};

struct GPParams {
    const unsigned short *U_bf, *q0sel_bf, *glast_bf, *c_bf;
    const unsigned short *wgih_bf, *wghh_bf, *wpih_bf, *wphh_bf;
    const float *bg_ih, *bg_hh, *bp_ih, *bp_hh;
    const float *g_last, *q0;
    const int *qm;
    float *g_out, *q_out;
    unsigned short *qssel_bf;
};

// ---------------------------------------------------------------------------
// f32 -> bf16 grid-stride conversion, 8 elems per iteration
// ---------------------------------------------------------------------------
__device__ __forceinline__ void cvt8(
    const float* __restrict__ src, unsigned short* __restrict__ dst,
    int n8, int gtid)
{
    for (int i = gtid; i < n8; i += AGSIZE) {
        const float4* s = reinterpret_cast<const float4*>(src + i * 8);
        const float4 v0 = s[0], v1 = s[1];
        ushort8 o = { f2bf(v0.x), f2bf(v0.y), f2bf(v0.z), f2bf(v0.w),
                      f2bf(v1.x), f2bf(v1.y), f2bf(v1.z), f2bf(v1.w) };
        *reinterpret_cast<ushort8*>(dst + i * 8) = o;
    }
}

// ---------------------------------------------------------------------------
// Kernel 1: cvt + gather prelude (grid-stride) then attention.
// Attn: one wave per b (proven r6 config), one pass, online softmax.
// c_ emitted in bf16. Kernel completion = barrier before GRUs.
// ---------------------------------------------------------------------------
__global__ __launch_bounds__(256) void attn_fused(AttnParams p)
{
    const int tid  = threadIdx.x;
    const int lane = tid & 63;
    const int wid  = tid >> 6;
    const int gtid = blockIdx.x * 256 + tid;

    const float* g_last = p.g_hist + (size_t)(T_N - 1) * BD;

    // ---- prelude: conversions + gather (grid-stride over whole grid) ----
    cvt8(p.wg_ih, p.wgih_bf, NG * 512 / 8, gtid);
    cvt8(p.wg_hh, p.wghh_bf, NG * 256 / 8, gtid);
    cvt8(p.wp_ih, p.wpih_bf, NG * 512 / 8, gtid);
    cvt8(p.wp_hh, p.wphh_bf, NG * 256 / 8, gtid);
    cvt8(p.we_ih, p.weih_bf, NG * 256 / 8, gtid);
    cvt8(p.we_hh, p.wehh_bf, NG * 256 / 8, gtid);
    cvt8(p.U,     p.U_bf,     B_N * D / 8, gtid);
    cvt8(p.e0,    p.e0_bf,    B_N * D / 8, gtid);
    cvt8(g_last,  p.glast_bf, B_N * D / 8, gtid);
    for (int i = gtid; i < B_N * D / 4; i += AGSIZE) {
        const int row = i >> 6;
        const int j   = (i & 63) * 4;
        const float4 v = *reinterpret_cast<const float4*>(
            p.q0 + ((size_t)row * P_N + p.qm[row]) * D + j);
        ushort4 bv = { f2bf(v.x), f2bf(v.y), f2bf(v.z), f2bf(v.w) };
        *reinterpret_cast<ushort4*>(p.q0sel_bf + (size_t)row * D + j) = bv;
    }

    // ---- attention: b = blockIdx.x*4 + wid ----
    const int b = blockIdx.x * 4 + wid;

    const float4 w4 = *reinterpret_cast<const float4*>(p.attn_w + lane * 4);
    const float* gbase = p.g_hist + (size_t)b * D + lane * 4;

    float  m = -INFINITY, l = 0.f;
    float4 acc = {0.f, 0.f, 0.f, 0.f};
    float  s0 = 0.f, s1 = 0.f;   // per-lane stash of raw scores (t&63==lane)

    auto step = [&](int t, const float4& g) {
        float dot = g.x * w4.x + g.y * w4.y + g.z * w4.z + g.w * w4.w;
        #pragma unroll
        for (int off = 32; off >= 1; off >>= 1)
            dot += __shfl_xor(dot, off, 64);
        const float mn   = fmaxf(m, dot);
        const float corr = __expf(m - mn);     // t==0: exp(-inf)=0 zeroes state
        const float pr   = __expf(dot - mn);
        l = l * corr + pr;
        acc.x = fmaf(pr, g.x, acc.x * corr);
        acc.y = fmaf(pr, g.y, acc.y * corr);
        acc.z = fmaf(pr, g.z, acc.z * corr);
        acc.w = fmaf(pr, g.w, acc.w * corr);
        m = mn;
        if ((t & 63) == lane) { if (t & 64) s1 = dot; else s0 = dot; }
    };

    for (int t = 0; t < T_N; t += 2) {
        const float4 g0 = *reinterpret_cast<const float4*>(gbase + (size_t)t * BD);
        const float4 g1 = *reinterpret_cast<const float4*>(gbase + (size_t)(t + 1) * BD);
        step(t, g0);
        step(t + 1, g1);
    }

    const float rl = 1.f / l;
    ushort4 cv = { f2bf(acc.x * rl), f2bf(acc.y * rl),
                   f2bf(acc.z * rl), f2bf(acc.w * rl) };
    *reinterpret_cast<ushort4*>(p.c_bf + (size_t)b * D + lane * 4) = cv;
    p.a_out[(size_t)b * T_N + lane]      = __expf(s0 - m) * rl;
    p.a_out[(size_t)b * T_N + 64 + lane] = __expf(s1 - m) * rl;
}

// ---------------------------------------------------------------------------
// Fused GRU tile body (round-6 proven): 128 A-rows x 32 gate-cols, BK=32,
// 16x16x32 MFMA, 4 waves, 3-deep pipelined global_load_lds staging with
// counted vmcnt; 16B-slot XOR swizzle phys = s ^ ((row>>1)&3) applied on the
// global SOURCE (linear LDS dest) and on the ds_read side.
// kcolA and kcolW SEPARATE (round-3 lesson). W-tile rows {c0,c0+256,c0+512}
// padded 96->128 by duplication.
//   MODE 0: out_f32[row*256+col] = val   (h = hsrc[row*256+col])
//   MODE 1: party — h = q0[row,qm,col]; writes q_out both slots + qs bf16
// ---------------------------------------------------------------------------
template<int MODE, int NI, int LDWI>
__device__ __forceinline__ void gru_body(
    int r0, int c0, unsigned short* smem, int tid,
    const unsigned short* __restrict__ A0,
    const unsigned short* __restrict__ A1,
    const unsigned short* __restrict__ Wi, const float* __restrict__ bi,
    const unsigned short* __restrict__ Ah,
    const unsigned short* __restrict__ Wh, const float* __restrict__ bh,
    const float* __restrict__ hsrc, const int* __restrict__ qm,
    float* __restrict__ out_f32, unsigned short* __restrict__ out_bf)
{
    constexpr int NT = NI + 8;

    const int lane = tid & 63;
    const int wid  = tid >> 6;
    const int st_row = lane >> 2;
    const int st_p   = lane & 3;

    f32x4 accI[2][6] = {};
    f32x4 accH[2][6] = {};

    auto stage = [&](int step, int buf) {
        const unsigned short* Apart;
        const unsigned short* W;
        int kcolA, kcolW, ldw;
        if (step < NI) {
            const int kt = step * 32;
            Apart = (kt < D) ? A0 : A1;
            kcolA = kt & (D - 1);
            kcolW = kt;
            W     = Wi;
            ldw   = LDWI;
        } else {
            const int kt = (step - NI) * 32;
            Apart = Ah; kcolA = kt; kcolW = kt; W = Wh; ldw = D;
        }
        unsigned short* As = smem + buf * 8192;
        unsigned short* Ws = As + 4096;
        #pragma unroll
        for (int c = 0; c < 2; ++c) {
            const int row  = wid * 32 + c * 16 + st_row;          // 0..127
            const int scol = (st_p ^ ((row >> 1) & 3)) * 8;       // swizzled src
            __builtin_amdgcn_global_load_lds(
                (const __attribute__((address_space(1))) void*)
                    (Apart + (size_t)(r0 + row) * D + kcolA + scol),
                (__attribute__((address_space(3))) void*)
                    (As + wid * 1024 + c * 512), 16, 0, 0);
            int grp = row >> 5; if (grp == 3) grp = 2;            // pad rows dup
            const int wrow = grp * 256 + c0 + (row & 31);
            __builtin_amdgcn_global_load_lds(
                (const __attribute__((address_space(1))) void*)
                    (W + (size_t)wrow * ldw + kcolW + scol),
                (__attribute__((address_space(3))) void*)
                    (Ws + wid * 1024 + c * 512), 16, 0, 0);
        }
    };

    auto compute = [&](int buf, f32x4 (&acc)[2][6]) {
        const unsigned short* As = smem + buf * 8192;
        const unsigned short* Ws = As + 4096;
        const int s  = lane >> 4;
        const int fr = lane & 15;
        bf16x8 a[2], b[6];
        #pragma unroll
        for (int m = 0; m < 2; ++m) {
            const int row = wid * 32 + m * 16 + fr;
            const int ph  = s ^ ((row >> 1) & 3);
            a[m] = *reinterpret_cast<const bf16x8*>(&As[row * 32 + ph * 8]);
        }
        #pragma unroll
        for (int j = 0; j < 6; ++j) {
            const int row = j * 16 + fr;
            const int ph  = s ^ ((row >> 1) & 3);
            b[j] = *reinterpret_cast<const bf16x8*>(&Ws[row * 32 + ph * 8]);
        }
        #pragma unroll
        for (int m = 0; m < 2; ++m)
            #pragma unroll
            for (int j = 0; j < 6; ++j)
                acc[m][j] = __builtin_amdgcn_mfma_f32_16x16x32_bf16(
                    a[m], b[j], acc[m][j], 0, 0, 0);
    };

    stage(0, 0);
    stage(1, 1);

    int cb = 0, ib = 2;
    for (int s = 0; s < NT; ++s) {
        if (s + 2 < NT) stage(s + 2, ib);
        const int rem = NT - 1 - s;
        if (rem >= 2)      asm volatile("s_waitcnt vmcnt(8)" ::: "memory");
        else if (rem == 1) asm volatile("s_waitcnt vmcnt(4)" ::: "memory");
        else               asm volatile("s_waitcnt vmcnt(0)" ::: "memory");
        __builtin_amdgcn_sched_barrier(0);
        __builtin_amdgcn_s_barrier();        // all waves' step-s writes visible
        if (s < NI) compute(cb, accI);
        else        compute(cb, accH);
        __builtin_amdgcn_s_barrier();        // reads done before buf rewrite
        cb = (cb == 2) ? 0 : cb + 1;
        ib = (ib == 2) ? 0 : ib + 1;
    }

    const int cr = (lane >> 4) * 4;
    const int cc = lane & 15;
    #pragma unroll
    for (int m = 0; m < 2; ++m) {
        #pragma unroll
        for (int jj = 0; jj < 2; ++jj) {
            const int col = c0 + jj * 16 + cc;
            const float bir = bi[col],       bhr = bh[col];
            const float biz = bi[col + 256], bhz = bh[col + 256];
            const float bin = bi[col + 512], bhn = bh[col + 512];
            #pragma unroll
            for (int q = 0; q < 4; ++q) {
                const int row = r0 + wid * 32 + m * 16 + cr + q;
                const float ir  = accI[m][jj][q]     + bir;
                const float hr  = accH[m][jj][q]     + bhr;
                const float iz  = accI[m][jj + 2][q] + biz;
                const float hz  = accH[m][jj + 2][q] + bhz;
                const float in_ = accI[m][jj + 4][q] + bin;
                const float hn  = accH[m][jj + 4][q] + bhn;
                const float rg = 1.f / (1.f + __expf(-(ir + hr)));
                const float zg = 1.f / (1.f + __expf(-(iz + hz)));
                const float ng = tanhf(in_ + rg * hn);
                if (MODE == 1) {
                    const int p = qm[row];
                    const float hv  = hsrc[(size_t)row * 512 + (size_t)p * 256 + col];
                    const float ov  = hsrc[(size_t)row * 512 + (size_t)(1 - p) * 256 + col];
                    const float val = (1.f - zg) * ng + zg * hv;
                    out_f32[(size_t)row * 512 + (size_t)p * 256 + col]       = val;
                    out_f32[(size_t)row * 512 + (size_t)(1 - p) * 256 + col] = ov;
                    out_bf[(size_t)row * 256 + col] = f2bf(val);
                } else {
                    const float hv  = hsrc[(size_t)row * 256 + col];
                    const float val = (1.f - zg) * ng + zg * hv;
                    out_f32[(size_t)row * 256 + col] = val;
                }
            }
        }
    }
}

// ---------------------------------------------------------------------------
// Kernel 2: global GRU (blocks 0..255) | party GRU (blocks 256..511).
// 512 blocks -> 2 blocks/CU -> 2 waves/SIMD of cross-block latency hiding.
// ---------------------------------------------------------------------------
__global__ __launch_bounds__(256) void gp_gru(GPParams p)
{
    __shared__ unsigned short smem[3 * 8192];   // 48 KB
    const int tid = threadIdx.x;
    const int bid = blockIdx.x;

    if (bid < 256) {
        const int r0 = (bid & 31) * 128, c0 = (bid >> 5) * 32;
        gru_body<0, 16, 512>(r0, c0, smem, tid,
            p.U_bf, p.q0sel_bf, p.wgih_bf, p.bg_ih,
            p.glast_bf, p.wghh_bf, p.bg_hh,
            p.g_last, nullptr, p.g_out, nullptr);
    } else {
        const int gb = bid - 256;
        const int r0 = (gb & 31) * 128, c0 = (gb >> 5) * 32;
        gru_body<1, 16, 512>(r0, c0, smem, tid,
            p.U_bf, p.c_bf, p.wpih_bf, p.bp_ih,
            p.q0sel_bf, p.wphh_bf, p.bp_hh,
            p.q0, p.qm, p.q_out, p.qssel_bf);
    }
}

// ---------------------------------------------------------------------------
// Kernel 3: emotion GRU (256 blocks).
// ---------------------------------------------------------------------------
__global__ __launch_bounds__(256) void e_gru(
    const unsigned short* __restrict__ qssel_bf,
    const unsigned short* __restrict__ weih_bf, const float* __restrict__ be_ih,
    const unsigned short* __restrict__ e0_bf,
    const unsigned short* __restrict__ wehh_bf, const float* __restrict__ be_hh,
    const float* __restrict__ e0, float* __restrict__ e_out)
{
    __shared__ unsigned short smem[3 * 8192];
    const int tid = threadIdx.x;
    const int bid = blockIdx.x;
    const int r0 = (bid & 31) * 128, c0 = (bid >> 5) * 32;
    gru_body<0, 8, 256>(r0, c0, smem, tid,
        qssel_bf, nullptr, weih_bf, be_ih,
        e0_bf, wehh_bf, be_hh,
        e0, nullptr, e_out, nullptr);
}

// ---------------------------------------------------------------------------
extern "C" void kernel_launch(void* const* d_in, const int* in_sizes, int n_in,
                              void* d_out, int out_size, void* d_ws, size_t ws_size,
                              hipStream_t stream)
{
    const float* U      = (const float*)d_in[0];
    const int*   qm     = (const int*)  d_in[1];
    const float* g_hist = (const float*)d_in[2];
    const float* q0     = (const float*)d_in[3];
    const float* e0     = (const float*)d_in[4];
    const float* wg_ih  = (const float*)d_in[5];
    const float* wg_hh  = (const float*)d_in[6];
    const float* bg_ih  = (const float*)d_in[7];
    const float* bg_hh  = (const float*)d_in[8];
    const float* wp_ih  = (const float*)d_in[9];
    const float* wp_hh  = (const float*)d_in[10];
    const float* bp_ih  = (const float*)d_in[11];
    const float* bp_hh  = (const float*)d_in[12];
    const float* we_ih  = (const float*)d_in[13];
    const float* we_hh  = (const float*)d_in[14];
    const float* be_ih  = (const float*)d_in[15];
    const float* be_hh  = (const float*)d_in[16];
    const float* attn_w = (const float*)d_in[17];

    float* out   = (float*)d_out;
    float* g_out = out;                       // [B, 256]
    float* q_out = out + 1048576;             // [B, 2, 256]
    float* e_out = out + 3145728;             // [B, 256]
    float* a_out = out + 4194304;             // [B, 1, 128]

    unsigned short* bf = (unsigned short*)d_ws;
    unsigned short* U_bf     = bf;
    unsigned short* e0_bf    = bf + 1048576;
    unsigned short* glast_bf = bf + 2097152;
    unsigned short* q0sel_bf = bf + 3145728;
    unsigned short* c_bf     = bf + 4194304;
    unsigned short* qssel_bf = bf + 5242880;
    unsigned short* wgih_bf  = bf + 6291456;
    unsigned short* wpih_bf  = bf + 6684672;
    unsigned short* wghh_bf  = bf + 7077888;
    unsigned short* wphh_bf  = bf + 7274496;
    unsigned short* weih_bf  = bf + 7471104;
    unsigned short* wehh_bf  = bf + 7667712;       // end 7864320 elems (15.7 MB)

    const float* g_last = g_hist + (size_t)(T_N - 1) * BD;

    AttnParams ap;
    ap.U = U; ap.g_hist = g_hist; ap.q0 = q0; ap.e0 = e0; ap.qm = qm;
    ap.wg_ih = wg_ih; ap.wg_hh = wg_hh; ap.wp_ih = wp_ih; ap.wp_hh = wp_hh;
    ap.we_ih = we_ih; ap.we_hh = we_hh; ap.attn_w = attn_w;
    ap.a_out = a_out;
    ap.U_bf = U_bf; ap.e0_bf = e0_bf; ap.glast_bf = glast_bf;
    ap.q0sel_bf = q0sel_bf; ap.c_bf = c_bf;
    ap.wgih_bf = wgih_bf; ap.wpih_bf = wpih_bf; ap.wghh_bf = wghh_bf;
    ap.wphh_bf = wphh_bf; ap.weih_bf = weih_bf; ap.wehh_bf = wehh_bf;

    GPParams gp;
    gp.U_bf = U_bf; gp.q0sel_bf = q0sel_bf; gp.glast_bf = glast_bf;
    gp.c_bf = c_bf;
    gp.wgih_bf = wgih_bf; gp.wghh_bf = wghh_bf;
    gp.wpih_bf = wpih_bf; gp.wphh_bf = wphh_bf;
    gp.bg_ih = bg_ih; gp.bg_hh = bg_hh; gp.bp_ih = bp_ih; gp.bp_hh = bp_hh;
    gp.g_last = g_last; gp.q0 = q0; gp.qm = qm;
    gp.g_out = g_out; gp.q_out = q_out; gp.qssel_bf = qssel_bf;

    const dim3 blk(256);
    attn_fused<<<AGRID, blk, 0, stream>>>(ap);
    gp_gru<<<512, blk, 0, stream>>>(gp);
    e_gru<<<256, blk, 0, stream>>>(
        qssel_bf, weih_bf, be_ih, e0_bf, wehh_bf, be_hh, e0, e_out);
}